// Round 20
// baseline (155.444 us; speedup 1.0000x reference)
//
#include <hip/hip_runtime.h>

#define BB 2
#define TT 2048
#define CC 1024
#define NHEAD 16
#define DHEAD 64

typedef __attribute__((ext_vector_type(8))) short short8;     // bf16x8 MFMA frag
typedef __attribute__((ext_vector_type(8))) unsigned short ushort8;
typedef __attribute__((ext_vector_type(4))) float floatx4;
typedef __attribute__((ext_vector_type(2))) unsigned int uintx2;

__device__ inline unsigned short f32_to_bf16_rne(float f) {
  unsigned u = __builtin_bit_cast(unsigned, f);
  unsigned r = (u + 0x7FFFu + ((u >> 16) & 1u)) >> 16;
  return (unsigned short)r;
}
__device__ inline unsigned cvt_pk_bf16(float lo, float hi) {
  unsigned r;
  asm("v_cvt_pk_bf16_f32 %0, %1, %2" : "=v"(r) : "v"(lo), "v"(hi));
  return r;
}
__device__ inline void gload_lds16(const void* g, void* l) {
  __builtin_amdgcn_global_load_lds(
      (const __attribute__((address_space(1))) void*)g,
      (__attribute__((address_space(3))) void*)l, 16, 0, 0);
}

// ---------------------------------------------------------------------------
// Fused prep kernel: x->bf16 cvt | W_attn transpose(+Q scale) | W_proj
// transpose | scaled bias.
// ---------------------------------------------------------------------------
__device__ inline void transpose_tile(const float* __restrict__ W,
                                      unsigned short* __restrict__ Wt,
                                      int K, int N, int scale_cut, float scl,
                                      int bx, int by, float (*T)[33]) {
  const int tx = threadIdx.x & 31;
  const int ty = threadIdx.x >> 5;
  const int r0 = by * 32, c0 = bx * 32;
#pragma unroll
  for (int i = 0; i < 4; ++i)
    T[ty + i * 8][tx] = W[(size_t)(r0 + ty + i * 8) * N + c0 + tx];
  __syncthreads();
#pragma unroll
  for (int i = 0; i < 4; ++i) {
    const int nrow = c0 + ty + i * 8;
    const float s = (nrow < scale_cut) ? scl : 1.0f;
    Wt[(size_t)nrow * K + r0 + tx] = f32_to_bf16_rne(T[tx][ty + i * 8] * s);
  }
}

__global__ __launch_bounds__(256) void prep_kernel(
    const float* __restrict__ x, const float* __restrict__ W_attn,
    const float* __restrict__ b_attn, const float* __restrict__ W_proj,
    unsigned short* __restrict__ xb, unsigned short* __restrict__ Wat,
    unsigned short* __restrict__ Wpt, float* __restrict__ bscl, float scl) {
  __shared__ float T[32][33];
  const int id = blockIdx.x;
  if (id < 4096) {
    const int i = (id * 256 + threadIdx.x) * 4;
    float4 v = *(const float4*)(x + i);
    ushort4 o;
    o.x = f32_to_bf16_rne(v.x);
    o.y = f32_to_bf16_rne(v.y);
    o.z = f32_to_bf16_rne(v.z);
    o.w = f32_to_bf16_rne(v.w);
    *(ushort4*)(xb + i) = o;
  } else if (id < 4096 + 3072) {
    const int t = id - 4096;
    transpose_tile(W_attn, Wat, CC, 3 * CC, CC, scl, t % 96, t / 96, T);
  } else if (id < 4096 + 3072 + 1024) {
    const int t = id - (4096 + 3072);
    transpose_tile(W_proj, Wpt, CC, CC, 0, 1.0f, t % 32, t / 32, T);
  } else {
    const int i = (id - 8192) * 256 + threadIdx.x;
    if (i < 3 * CC) bscl[i] = b_attn[i] * (i < CC ? scl : 1.0f);
  }
}

// ---------------------------------------------------------------------------
// V part of qkv (bf16, [B,T,3C] at col 2C+h*64) -> vT[b][h][d][T]
// ---------------------------------------------------------------------------
__global__ __launch_bounds__(256) void transpose_v_kernel(
    const unsigned short* __restrict__ qkv, unsigned short* __restrict__ vT) {
  __shared__ unsigned short Ts[64][72];
  const int tt0 = blockIdx.x * 64;
  const int bh = blockIdx.y;
  const int h = bh & (NHEAD - 1);
  const int b = bh >> 4;
  const int tid = threadIdx.x;
  const unsigned short* src = qkv + (size_t)(b * TT) * (3 * CC) + 2 * CC + h * DHEAD;
#pragma unroll
  for (int it = 0; it < 2; ++it) {
    const int t = it * 32 + (tid >> 3);
    const int d8 = (tid & 7) * 8;
    ushort8 v = *(const ushort8*)(src + (size_t)(tt0 + t) * (3 * CC) + d8);
#pragma unroll
    for (int j = 0; j < 8; ++j) Ts[t][d8 + j] = v[j];
  }
  __syncthreads();
  unsigned short* dst = vT + ((size_t)((b * NHEAD + h) * DHEAD)) * TT;
#pragma unroll
  for (int it = 0; it < 2; ++it) {
    const int d = it * 32 + (tid >> 3);
    const int t8 = (tid & 7) * 8;
    ushort8 o;
#pragma unroll
    for (int j = 0; j < 8; ++j) o[j] = Ts[t8 + j][d];
    *(ushort8*)(dst + (size_t)d * TT + tt0 + t8) = o;
  }
}

// ---------------------------------------------------------------------------
// GEMM1: 128x192 tile, BK=32, 4 waves, 512 blocks (2/CU), THREE LDS buffers
// + depth-2 prefetch, counted vmcnt(5), one barrier/tile.
// ---------------------------------------------------------------------------
__global__ __launch_bounds__(256) void gemm1_kernel(
    const unsigned short* __restrict__ A,   // [M][K] bf16
    const unsigned short* __restrict__ Bt,  // [N][K] bf16
    const float* __restrict__ bias,
    unsigned short* __restrict__ C,         // [M][N] bf16
    int M, int N, int K) {
  __shared__ unsigned short SA[3][128 * 32];  // 24KB
  __shared__ unsigned short SB[3][192 * 32];  // 36KB

  const int id = blockIdx.x;
  const int xcd = id & 7;
  const int j = id >> 3;                      // 0..63
  const int row0 = (xcd * 4 + (j >> 4)) * 128;
  const int col0 = (j & 15) * 192;

  const int tid = threadIdx.x;
  const int w = tid >> 6;                     // 0..3
  const int lane = tid & 63;
  const int l15 = lane & 15;
  const int l4 = lane >> 4;
  const int wr = (w >> 1) * 64;
  const int wc = (w & 1) * 96;
  const int sr = lane >> 2;
  const int sc = lane & 3;

  floatx4 acc[4][6];
#pragma unroll
  for (int m = 0; m < 4; ++m)
#pragma unroll
    for (int n = 0; n < 6; ++n) acc[m][n] = (floatx4){0.f, 0.f, 0.f, 0.f};

  auto stage = [&](int t) {
    const int buf = t % 3;
    const int k0 = t * 32;
#pragma unroll
    for (int u5 = 0; u5 < 5; ++u5) {
      const int u = u5 * 4 + w;
      if (u < 8) {
        const int r = u * 16 + sr;
        gload_lds16(A + (size_t)(row0 + r) * K + k0 + ((sc ^ ((r >> 1) & 3)) * 8),
                    (char*)SA[buf] + u * 1024);
      } else {
        const int r = (u - 8) * 16 + sr;
        gload_lds16(Bt + (size_t)(col0 + r) * K + k0 + ((sc ^ ((r >> 1) & 3)) * 8),
                    (char*)SB[buf] + (u - 8) * 1024);
      }
    }
  };

  stage(0);
  stage(1);
  asm volatile("s_waitcnt vmcnt(5)" ::: "memory");
  __builtin_amdgcn_s_barrier();

  const int NT = K / 32;  // 32
  for (int t = 0; t < NT; ++t) {
    const unsigned short* sa = SA[t % 3];
    const unsigned short* sb = SB[t % 3];

    short8 af[4], bf[6];
#pragma unroll
    for (int n = 0; n < 6; ++n) {
      const int rb = wc + n * 16 + l15;
      bf[n] = *(const short8*)(sb + rb * 32 + ((l4 ^ ((rb >> 1) & 3)) * 8));
    }
#pragma unroll
    for (int m = 0; m < 4; ++m) {
      const int ra = wr + m * 16 + l15;
      af[m] = *(const short8*)(sa + ra * 32 + ((l4 ^ ((ra >> 1) & 3)) * 8));
    }
    if (t + 2 < NT) stage(t + 2);

    __builtin_amdgcn_s_setprio(1);
#pragma unroll
    for (int m = 0; m < 4; ++m)
#pragma unroll
      for (int n = 0; n < 6; ++n)
        acc[m][n] = __builtin_amdgcn_mfma_f32_16x16x32_bf16(af[m], bf[n], acc[m][n], 0, 0, 0);
    __builtin_amdgcn_s_setprio(0);

    if (t + 1 < NT) {
      if (t + 2 < NT)
        asm volatile("s_waitcnt vmcnt(5)" ::: "memory");
      else
        asm volatile("s_waitcnt vmcnt(0)" ::: "memory");
      __builtin_amdgcn_s_barrier();
    }
  }

  const int rg = l4 * 4;
#pragma unroll
  for (int m = 0; m < 4; ++m) {
#pragma unroll
    for (int n = 0; n < 6; ++n) {
      const int col = col0 + wc + n * 16 + l15;
      const float bv = bias[col];
#pragma unroll
      for (int r = 0; r < 4; ++r) {
        const int row = row0 + wr + m * 16 + rg + r;
        C[(size_t)row * N + col] = f32_to_bf16_rne(acc[m][n][r] + bv);
      }
    }
  }
}

// ---------------------------------------------------------------------------
// GEMM2: out[M][1024] fp32 = y @ Wpt^T + b_proj.
// 128x64 tile, BK=32, 4 waves; THREE LDS buffers + counted vmcnt(3).
// ---------------------------------------------------------------------------
__global__ __launch_bounds__(256) void gemm2_kernel(
    const unsigned short* __restrict__ A,   // [M][K] bf16 (y)
    const unsigned short* __restrict__ Bt,  // [N][K] bf16 (W_proj^T)
    const float* __restrict__ bias,
    float* __restrict__ C,                  // [M][N] fp32
    int M, int N, int K) {
  __shared__ unsigned short SA[3][128 * 32];  // 24KB
  __shared__ unsigned short SB[3][64 * 32];   // 12KB

  const int id = blockIdx.x;
  const int xcd = id & 7;
  const int j = id >> 3;                      // 0..63
  const int col0 = (xcd * 2 + (j >= 32 ? 1 : 0)) * 64;
  const int row0 = (j & 31) * 128;

  const int tid = threadIdx.x;
  const int w = tid >> 6;                     // 0..3
  const int lane = tid & 63;
  const int l15 = lane & 15;
  const int l4 = lane >> 4;
  const int wr = (w >> 1) * 64;
  const int wc = (w & 1) * 32;
  const int sr = lane >> 2;
  const int sc = lane & 3;

  floatx4 acc[4][2];
#pragma unroll
  for (int m = 0; m < 4; ++m)
#pragma unroll
    for (int n = 0; n < 2; ++n) acc[m][n] = (floatx4){0.f, 0.f, 0.f, 0.f};

  auto stage = [&](int t) {
    const int buf = t % 3;
    const int k0 = t * 32;
#pragma unroll
    for (int l = 0; l < 2; ++l) {
      const int r = w * 16 + sr + l * 64;
      gload_lds16(A + (size_t)(row0 + r) * K + k0 + ((sc ^ ((r >> 1) & 3)) * 8),
                  (char*)SA[buf] + (w * 16 + l * 64) * 64);
    }
    {
      const int r = w * 16 + sr;
      gload_lds16(Bt + (size_t)(col0 + r) * K + k0 + ((sc ^ ((r >> 1) & 3)) * 8),
                  (char*)SB[buf] + (w * 16) * 64);
    }
  };

  stage(0);
  stage(1);
  asm volatile("s_waitcnt vmcnt(3)" ::: "memory");
  __builtin_amdgcn_s_barrier();

  const int NT = K / 32;  // 32
  for (int t = 0; t < NT; ++t) {
    const unsigned short* sa = SA[t % 3];
    const unsigned short* sb = SB[t % 3];

    short8 af[4], bf[2];
#pragma unroll
    for (int n = 0; n < 2; ++n) {
      const int rb = wc + n * 16 + l15;
      bf[n] = *(const short8*)(sb + rb * 32 + ((l4 ^ ((rb >> 1) & 3)) * 8));
    }
#pragma unroll
    for (int m = 0; m < 4; ++m) {
      const int ra = wr + m * 16 + l15;
      af[m] = *(const short8*)(sa + ra * 32 + ((l4 ^ ((ra >> 1) & 3)) * 8));
    }
    if (t + 2 < NT) stage(t + 2);

    __builtin_amdgcn_s_setprio(1);
#pragma unroll
    for (int m = 0; m < 4; ++m)
#pragma unroll
      for (int n = 0; n < 2; ++n)
        acc[m][n] = __builtin_amdgcn_mfma_f32_16x16x32_bf16(af[m], bf[n], acc[m][n], 0, 0, 0);
    __builtin_amdgcn_s_setprio(0);

    if (t + 1 < NT) {
      if (t + 2 < NT)
        asm volatile("s_waitcnt vmcnt(3)" ::: "memory");
      else
        asm volatile("s_waitcnt vmcnt(0)" ::: "memory");
      __builtin_amdgcn_s_barrier();
    }
  }

  const int rg = l4 * 4;
#pragma unroll
  for (int m = 0; m < 4; ++m) {
#pragma unroll
    for (int n = 0; n < 2; ++n) {
      const int col = col0 + wc + n * 16 + l15;
      const float bv = bias[col];
#pragma unroll
      for (int r = 0; r < 4; ++r) {
        const int row = row0 + wr + m * 16 + rg + r;
        C[(size_t)row * N + col] = acc[m][n][r] + bv;
      }
    }
  }
}

// ---------------------------------------------------------------------------
// MFMA flash attention v10: 8 waves x 16 q-rows = 128-row q tiles, KVBLK=128.
// Paired-qt uniform blocks (qtA=15-p, qtB=p in 128-units; 17 tiles each),
// 256 blocks of 512 thr, LDS 80KB (K dbuf 32 + V^T dbuf 32 + P 16).
// Per-token fixed costs (barriers/vmcnt/softmax branch) halve vs v9; staging
// is 4 gloads/wave. Diagonal tiles skip wave-uniformly-masked MFMA clusters
// (chunk f fully masked iff f > wq). Per-wave math identical to v9.
// ---------------------------------------------------------------------------
__global__ __launch_bounds__(512) void flash_mfma_kernel(
    const unsigned short* __restrict__ qkv,
    const unsigned short* __restrict__ vT,
    unsigned short* __restrict__ y) {
  __shared__ unsigned short Ks[2][128 * 64];  // 32KB [token][d-chunk swz]
  __shared__ unsigned short Vs[2][64 * 128];  // 32KB [d][tok-chunk swz]
  __shared__ unsigned short Ps[8][16 * 64];   // 16KB per-wave P (sub-phase)

  const int id = blockIdx.x;           // 256 blocks
  const int xcd = id & 7;
  const int grp = (id >> 3) & 3;
  const int p = id >> 5;               // 0..7
  const int bh = xcd * 4 + grp;
  const int qtA = 15 - p, qtB = p;     // 128-row q tiles
  const int ntA = qtA + 1, ntB = qtB + 1;  // total 17 for every block

  const int h = bh & (NHEAD - 1);
  const int b = bh >> 4;
  const int tid = threadIdx.x;
  const int wq = tid >> 6;             // 0..7
  const int lane = tid & 63;
  const int l15 = lane & 15;
  const int l4 = lane >> 4;

  const size_t baseQ = (size_t)(b * TT) * (3 * CC) + h * DHEAD;
  const size_t baseK = baseQ + CC;
  const size_t vbase = (size_t)((b * NHEAD + h) * DHEAD) * TT;

  short8 aqA[2], aqB[2];
  {
    const unsigned short* qp =
        qkv + baseQ + (size_t)(qtA * 128 + wq * 16 + l15) * (3 * CC) + l4 * 8;
    aqA[0] = *(const short8*)(qp);
    aqA[1] = *(const short8*)(qp + 32);
    const unsigned short* qp2 =
        qkv + baseQ + (size_t)(qtB * 128 + wq * 16 + l15) * (3 * CC) + l4 * 8;
    aqB[0] = *(const short8*)(qp2);
    aqB[1] = *(const short8*)(qp2 + 32);
  }

  floatx4 accT[4];
  float m_i = -1e30f, l_i = 0.f;   // l_i per-lane partial
#pragma unroll
  for (int n = 0; n < 4; ++n) accT[n] = (floatx4){0.f, 0.f, 0.f, 0.f};

  // stage tile (128 tokens): per wave 2 K-units + 2 V-units (4 gloads)
  auto stage = [&](int KT, int BUF) {
#pragma unroll
    for (int uu = 0; uu < 2; ++uu) {
      const int u = uu * 8 + wq;            // 0..15, wave-uniform
      const int kr = u * 8 + (lane >> 3);   // K token row
      gload_lds16(qkv + baseK + (size_t)(KT * 128 + kr) * (3 * CC) +
                      (((lane & 7) ^ (kr & 7)) * 8),
                  (char*)Ks[BUF] + u * 1024);
      const int vd = u * 4 + (lane >> 4);   // V d row
      gload_lds16(vT + vbase + (size_t)vd * TT + KT * 128 +
                      (((lane & 15) ^ (vd & 15)) * 8),
                  (char*)Vs[BUF] + u * 1024);
    }
  };

  auto epilogue = [&](int qt) {
    char* Pw = (char*)Ps[wq];
    float lsum = l_i;
    lsum += __shfl_xor(lsum, 16, 64);
    lsum += __shfl_xor(lsum, 32, 64);
    const float inv = 1.0f / lsum;
#pragma unroll
    for (int nd = 0; nd < 4; ++nd) {
      uintx2 dw;
      dw[0] = cvt_pk_bf16(accT[nd][0] * inv, accT[nd][1] * inv);
      dw[1] = cvt_pk_bf16(accT[nd][2] * inv, accT[nd][3] * inv);
      const int c = nd * 2 + (l4 >> 1);
      *(uintx2*)(Pw + l15 * 128 + ((c ^ (l15 & 7)) * 16) + (l4 & 1) * 8) = dw;
    }
    asm volatile("s_waitcnt lgkmcnt(0)" ::: "memory");
#pragma unroll
    for (int ch = 0; ch < 2; ++ch) {
      const int q16 = lane >> 2;
      const int c = ch * 4 + (lane & 3);
      ushort8 o = *(const ushort8*)(Pw + q16 * 128 + ((c ^ (q16 & 7)) * 16));
      const int qg = qt * 128 + wq * 16 + q16;
      *(ushort8*)(y + (size_t)(b * TT + qg) * CC + h * DHEAD + c * 8) = o;
    }
  };

  const int nt_total = ntA + ntB;  // 17

  stage(0, 0);
  asm volatile("s_waitcnt vmcnt(0)" ::: "memory");
  __builtin_amdgcn_s_barrier();

  for (int t = 0; t < nt_total; ++t) {
    const bool phB = (t >= ntA);
    const int kt = phB ? t - ntA : t;
    const int qtcur = phB ? qtB : qtA;
    const int qminw = qtcur * 128 + wq * 16;
    const bool diag = (kt == qtcur);
    const int cur = t & 1;
    if (t + 1 < nt_total)
      stage((t + 1 >= ntA) ? t + 1 - ntA : t + 1, cur ^ 1);

    // ---- S^T = K Q^T : up to 16 MFMA; skip wave-uniformly-masked chunks ----
    floatx4 sa[8];
#pragma unroll
    for (int f = 0; f < 8; ++f) sa[f] = (floatx4){0.f, 0.f, 0.f, 0.f};

    __builtin_amdgcn_s_setprio(1);
#pragma unroll
    for (int kc = 0; kc < 2; ++kc) {
      const short8 aq = phB ? aqB[kc] : aqA[kc];
#pragma unroll
      for (int f = 0; f < 8; ++f) {
        if (!diag || f <= wq) {
          const int row = 16 * f + l15;
          short8 bk = *(const short8*)(Ks[cur] + row * 64 +
                                       ((kc * 4 + l4) ^ (row & 7)) * 8);
          sa[f] = __builtin_amdgcn_mfma_f32_16x16x32_bf16(bk, aq, sa[f], 0, 0, 0);
        }
      }
    }
    __builtin_amdgcn_s_setprio(0);

    // ---- mask + de-shuffled online softmax (log2 domain) ----
    const int qg = qminw + l15;
    if (kt * 128 + 127 > qminw) {
#pragma unroll
      for (int f = 0; f < 8; ++f)
#pragma unroll
        for (int r = 0; r < 4; ++r) {
          const int kg = kt * 128 + f * 16 + l4 * 4 + r;
          if (kg > qg) sa[f][r] = -1e30f;
        }
    }
    float rm = -1e30f;
#pragma unroll
    for (int f = 0; f < 8; ++f)
      rm = fmaxf(rm, fmaxf(fmaxf(sa[f][0], sa[f][1]), fmaxf(sa[f][2], sa[f][3])));

    float rs = 0.f;
    if (__all(rm <= m_i + 8.0f)) {
#pragma unroll
      for (int f = 0; f < 8; ++f)
#pragma unroll
        for (int r = 0; r < 4; ++r) {
          const float pv = __builtin_amdgcn_exp2f(sa[f][r] - m_i);
          sa[f][r] = pv;
          rs += pv;
        }
      l_i += rs;
    } else {
      rm = fmaxf(rm, __shfl_xor(rm, 16, 64));
      rm = fmaxf(rm, __shfl_xor(rm, 32, 64));
      const float mn = fmaxf(m_i, rm);
      const float scale = __builtin_amdgcn_exp2f(m_i - mn);
#pragma unroll
      for (int f = 0; f < 8; ++f)
#pragma unroll
        for (int r = 0; r < 4; ++r) {
          const float pv = __builtin_amdgcn_exp2f(sa[f][r] - mn);
          sa[f][r] = pv;
          rs += pv;
        }
      l_i = l_i * scale + rs;
      m_i = mn;
#pragma unroll
      for (int nd = 0; nd < 4; ++nd) accT[nd] *= scale;
    }

    // ---- P -> LDS -> PV in two k-sub-phases (64 tokens each) ----
    char* Pg = (char*)Ps[wq];
#pragma unroll
    for (int ph = 0; ph < 2; ++ph) {
#pragma unroll
      for (int fp = 0; fp < 4; ++fp) {
        const int f = ph * 4 + fp;
        uintx2 dw;
        dw[0] = cvt_pk_bf16(sa[f][0], sa[f][1]);
        dw[1] = cvt_pk_bf16(sa[f][2], sa[f][3]);
        const int c = fp * 2 + (l4 >> 1);
        *(uintx2*)(Pg + l15 * 128 + ((c ^ (l15 & 7)) * 16) + (l4 & 1) * 8) = dw;
      }
      asm volatile("s_waitcnt lgkmcnt(0)" ::: "memory");  // same-wave RAW

      short8 pb[2];
#pragma unroll
      for (int kc2 = 0; kc2 < 2; ++kc2) {
        const int c = kc2 * 4 + l4;
        pb[kc2] = *(const short8*)(Pg + l15 * 128 + ((c ^ (l15 & 7)) * 16));
      }

      __builtin_amdgcn_s_setprio(1);
#pragma unroll
      for (int kc2 = 0; kc2 < 2; ++kc2) {
        const int kcg = ph * 2 + kc2;   // global 32-token chunk 0..3
        if (!diag || kcg * 2 <= wq) {   // skip fully-masked PV clusters
#pragma unroll
          for (int nd = 0; nd < 4; ++nd) {
            const int row = 16 * nd + l15;
            short8 vb = *(const short8*)(Vs[cur] + row * 128 +
                                         (((kcg * 4 + l4) ^ (row & 15)) * 8));
            accT[nd] = __builtin_amdgcn_mfma_f32_16x16x32_bf16(vb, pb[kc2], accT[nd], 0, 0, 0);
          }
        }
      }
      __builtin_amdgcn_s_setprio(0);
    }

    asm volatile("s_waitcnt vmcnt(0)" ::: "memory");
    __builtin_amdgcn_s_barrier();

    if (t == ntA - 1) {
      epilogue(qtA);
      m_i = -1e30f;
      l_i = 0.f;
#pragma unroll
      for (int n = 0; n < 4; ++n) accT[n] = (floatx4){0.f, 0.f, 0.f, 0.f};
    }
  }

  epilogue(qtB);
}

extern "C" void kernel_launch(void* const* d_in, const int* in_sizes, int n_in,
                              void* d_out, int out_size, void* d_ws, size_t ws_size,
                              hipStream_t stream) {
  const float* x      = (const float*)d_in[0];
  const float* W_attn = (const float*)d_in[1];
  const float* b_attn = (const float*)d_in[2];
  const float* W_proj = (const float*)d_in[3];
  const float* b_proj = (const float*)d_in[4];
  float* out = (float*)d_out;

  const int M = BB * TT;  // 4096
  const float SCL = 0.125f * 1.44269504089f;  // 1/sqrt(64) * log2(e)

  // workspace layout (ushort units)
  unsigned short* qkvb = (unsigned short*)d_ws;          // M * 3C
  unsigned short* xb   = qkvb + (size_t)M * 3 * CC;      // M * C
  unsigned short* Wat  = xb + (size_t)M * CC;            // 3C * C
  unsigned short* Wpt  = Wat + (size_t)3 * CC * CC;      // C * C
  unsigned short* yb   = Wpt + (size_t)CC * CC;          // M * C
  unsigned short* vTb  = yb + (size_t)M * CC;            // B*H*D*T
  float* bscl = (float*)(vTb + (size_t)BB * NHEAD * DHEAD * TT);  // 3C floats

  prep_kernel<<<8204, 256, 0, stream>>>(x, W_attn, b_attn, W_proj,
                                        xb, Wat, Wpt, bscl, SCL);

  // GEMM1: qkv = x @ W_attn + b_attn (128x192, 512 blocks = 2/CU, counted)
  gemm1_kernel<<<512, 256, 0, stream>>>(xb, Wat, bscl, qkvb, M, 3 * CC, CC);

  // V -> vT[b][h][d][T]
  {
    dim3 grid(TT / 64, BB * NHEAD);
    transpose_v_kernel<<<grid, 256, 0, stream>>>(qkvb, vTb);
  }

  // MFMA flash attention (8 waves, 128-row q tiles, KVBLK=128, paired-qt)
  flash_mfma_kernel<<<256, 512, 0, stream>>>(qkvb, vTb, yb);

  // GEMM2: out = y @ W_proj + b_proj (counted-vmcnt pipeline, fp32 out)
  gemm2_kernel<<<512, 256, 0, stream>>>(yb, Wpt, b_proj, out, M, CC, CC);
}

// Round 21
// 104.764 us; speedup vs baseline: 1.4838x; 1.4838x over previous
//
#include <hip/hip_runtime.h>

#define BB 2
#define TT 2048
#define CC 1024
#define NHEAD 16
#define DHEAD 64

typedef __attribute__((ext_vector_type(8))) short short8;     // bf16x8 MFMA frag
typedef __attribute__((ext_vector_type(8))) unsigned short ushort8;
typedef __attribute__((ext_vector_type(4))) float floatx4;
typedef __attribute__((ext_vector_type(2))) unsigned int uintx2;

__device__ inline unsigned short f32_to_bf16_rne(float f) {
  unsigned u = __builtin_bit_cast(unsigned, f);
  unsigned r = (u + 0x7FFFu + ((u >> 16) & 1u)) >> 16;
  return (unsigned short)r;
}
__device__ inline unsigned cvt_pk_bf16(float lo, float hi) {
  unsigned r;
  asm("v_cvt_pk_bf16_f32 %0, %1, %2" : "=v"(r) : "v"(lo), "v"(hi));
  return r;
}
__device__ inline void gload_lds16(const void* g, void* l) {
  __builtin_amdgcn_global_load_lds(
      (const __attribute__((address_space(1))) void*)g,
      (__attribute__((address_space(3))) void*)l, 16, 0, 0);
}

// ---------------------------------------------------------------------------
// Fused prep kernel: x->bf16 cvt | W_attn transpose(+Q scale) | W_proj
// transpose | scaled bias.
// ---------------------------------------------------------------------------
__device__ inline void transpose_tile(const float* __restrict__ W,
                                      unsigned short* __restrict__ Wt,
                                      int K, int N, int scale_cut, float scl,
                                      int bx, int by, float (*T)[33]) {
  const int tx = threadIdx.x & 31;
  const int ty = threadIdx.x >> 5;
  const int r0 = by * 32, c0 = bx * 32;
#pragma unroll
  for (int i = 0; i < 4; ++i)
    T[ty + i * 8][tx] = W[(size_t)(r0 + ty + i * 8) * N + c0 + tx];
  __syncthreads();
#pragma unroll
  for (int i = 0; i < 4; ++i) {
    const int nrow = c0 + ty + i * 8;
    const float s = (nrow < scale_cut) ? scl : 1.0f;
    Wt[(size_t)nrow * K + r0 + tx] = f32_to_bf16_rne(T[tx][ty + i * 8] * s);
  }
}

__global__ __launch_bounds__(256) void prep_kernel(
    const float* __restrict__ x, const float* __restrict__ W_attn,
    const float* __restrict__ b_attn, const float* __restrict__ W_proj,
    unsigned short* __restrict__ xb, unsigned short* __restrict__ Wat,
    unsigned short* __restrict__ Wpt, float* __restrict__ bscl, float scl) {
  __shared__ float T[32][33];
  const int id = blockIdx.x;
  if (id < 4096) {
    const int i = (id * 256 + threadIdx.x) * 4;
    float4 v = *(const float4*)(x + i);
    ushort4 o;
    o.x = f32_to_bf16_rne(v.x);
    o.y = f32_to_bf16_rne(v.y);
    o.z = f32_to_bf16_rne(v.z);
    o.w = f32_to_bf16_rne(v.w);
    *(ushort4*)(xb + i) = o;
  } else if (id < 4096 + 3072) {
    const int t = id - 4096;
    transpose_tile(W_attn, Wat, CC, 3 * CC, CC, scl, t % 96, t / 96, T);
  } else if (id < 4096 + 3072 + 1024) {
    const int t = id - (4096 + 3072);
    transpose_tile(W_proj, Wpt, CC, CC, 0, 1.0f, t % 32, t / 32, T);
  } else {
    const int i = (id - 8192) * 256 + threadIdx.x;
    if (i < 3 * CC) bscl[i] = b_attn[i] * (i < CC ? scl : 1.0f);
  }
}

// ---------------------------------------------------------------------------
// V part of qkv (bf16, [B,T,3C] at col 2C+h*64) -> vT[b][h][d][T]
// ---------------------------------------------------------------------------
__global__ __launch_bounds__(256) void transpose_v_kernel(
    const unsigned short* __restrict__ qkv, unsigned short* __restrict__ vT) {
  __shared__ unsigned short Ts[64][72];
  const int tt0 = blockIdx.x * 64;
  const int bh = blockIdx.y;
  const int h = bh & (NHEAD - 1);
  const int b = bh >> 4;
  const int tid = threadIdx.x;
  const unsigned short* src = qkv + (size_t)(b * TT) * (3 * CC) + 2 * CC + h * DHEAD;
#pragma unroll
  for (int it = 0; it < 2; ++it) {
    const int t = it * 32 + (tid >> 3);
    const int d8 = (tid & 7) * 8;
    ushort8 v = *(const ushort8*)(src + (size_t)(tt0 + t) * (3 * CC) + d8);
#pragma unroll
    for (int j = 0; j < 8; ++j) Ts[t][d8 + j] = v[j];
  }
  __syncthreads();
  unsigned short* dst = vT + ((size_t)((b * NHEAD + h) * DHEAD)) * TT;
#pragma unroll
  for (int it = 0; it < 2; ++it) {
    const int d = it * 32 + (tid >> 3);
    const int t8 = (tid & 7) * 8;
    ushort8 o;
#pragma unroll
    for (int j = 0; j < 8; ++j) o[j] = Ts[t8 + j][d];
    *(ushort8*)(dst + (size_t)d * TT + tt0 + t8) = o;
  }
}

// ---------------------------------------------------------------------------
// GEMM1: 128x192 tile, BK=32, 4 waves, 512 blocks (2/CU), THREE LDS buffers
// + depth-2 prefetch, counted vmcnt(5), one barrier/tile.
// ---------------------------------------------------------------------------
__global__ __launch_bounds__(256) void gemm1_kernel(
    const unsigned short* __restrict__ A,   // [M][K] bf16
    const unsigned short* __restrict__ Bt,  // [N][K] bf16
    const float* __restrict__ bias,
    unsigned short* __restrict__ C,         // [M][N] bf16
    int M, int N, int K) {
  __shared__ unsigned short SA[3][128 * 32];  // 24KB
  __shared__ unsigned short SB[3][192 * 32];  // 36KB

  const int id = blockIdx.x;
  const int xcd = id & 7;
  const int j = id >> 3;                      // 0..63
  const int row0 = (xcd * 4 + (j >> 4)) * 128;
  const int col0 = (j & 15) * 192;

  const int tid = threadIdx.x;
  const int w = tid >> 6;                     // 0..3
  const int lane = tid & 63;
  const int l15 = lane & 15;
  const int l4 = lane >> 4;
  const int wr = (w >> 1) * 64;
  const int wc = (w & 1) * 96;
  const int sr = lane >> 2;
  const int sc = lane & 3;

  floatx4 acc[4][6];
#pragma unroll
  for (int m = 0; m < 4; ++m)
#pragma unroll
    for (int n = 0; n < 6; ++n) acc[m][n] = (floatx4){0.f, 0.f, 0.f, 0.f};

  auto stage = [&](int t) {
    const int buf = t % 3;
    const int k0 = t * 32;
#pragma unroll
    for (int u5 = 0; u5 < 5; ++u5) {
      const int u = u5 * 4 + w;
      if (u < 8) {
        const int r = u * 16 + sr;
        gload_lds16(A + (size_t)(row0 + r) * K + k0 + ((sc ^ ((r >> 1) & 3)) * 8),
                    (char*)SA[buf] + u * 1024);
      } else {
        const int r = (u - 8) * 16 + sr;
        gload_lds16(Bt + (size_t)(col0 + r) * K + k0 + ((sc ^ ((r >> 1) & 3)) * 8),
                    (char*)SB[buf] + (u - 8) * 1024);
      }
    }
  };

  stage(0);
  stage(1);
  asm volatile("s_waitcnt vmcnt(5)" ::: "memory");
  __builtin_amdgcn_s_barrier();

  const int NT = K / 32;  // 32
  for (int t = 0; t < NT; ++t) {
    const unsigned short* sa = SA[t % 3];
    const unsigned short* sb = SB[t % 3];

    short8 af[4], bf[6];
#pragma unroll
    for (int n = 0; n < 6; ++n) {
      const int rb = wc + n * 16 + l15;
      bf[n] = *(const short8*)(sb + rb * 32 + ((l4 ^ ((rb >> 1) & 3)) * 8));
    }
#pragma unroll
    for (int m = 0; m < 4; ++m) {
      const int ra = wr + m * 16 + l15;
      af[m] = *(const short8*)(sa + ra * 32 + ((l4 ^ ((ra >> 1) & 3)) * 8));
    }
    if (t + 2 < NT) stage(t + 2);

    __builtin_amdgcn_s_setprio(1);
#pragma unroll
    for (int m = 0; m < 4; ++m)
#pragma unroll
      for (int n = 0; n < 6; ++n)
        acc[m][n] = __builtin_amdgcn_mfma_f32_16x16x32_bf16(af[m], bf[n], acc[m][n], 0, 0, 0);
    __builtin_amdgcn_s_setprio(0);

    if (t + 1 < NT) {
      if (t + 2 < NT)
        asm volatile("s_waitcnt vmcnt(5)" ::: "memory");
      else
        asm volatile("s_waitcnt vmcnt(0)" ::: "memory");
      __builtin_amdgcn_s_barrier();
    }
  }

  const int rg = l4 * 4;
#pragma unroll
  for (int m = 0; m < 4; ++m) {
#pragma unroll
    for (int n = 0; n < 6; ++n) {
      const int col = col0 + wc + n * 16 + l15;
      const float bv = bias[col];
#pragma unroll
      for (int r = 0; r < 4; ++r) {
        const int row = row0 + wr + m * 16 + rg + r;
        C[(size_t)row * N + col] = f32_to_bf16_rne(acc[m][n][r] + bv);
      }
    }
  }
}

// ---------------------------------------------------------------------------
// GEMM2: out[M][1024] fp32 = y @ Wpt^T + b_proj.
// 128x64 tile, BK=32, 4 waves; THREE LDS buffers + counted vmcnt(3).
// ---------------------------------------------------------------------------
__global__ __launch_bounds__(256) void gemm2_kernel(
    const unsigned short* __restrict__ A,   // [M][K] bf16 (y)
    const unsigned short* __restrict__ Bt,  // [N][K] bf16 (W_proj^T)
    const float* __restrict__ bias,
    float* __restrict__ C,                  // [M][N] fp32
    int M, int N, int K) {
  __shared__ unsigned short SA[3][128 * 32];  // 24KB
  __shared__ unsigned short SB[3][64 * 32];   // 12KB

  const int id = blockIdx.x;
  const int xcd = id & 7;
  const int j = id >> 3;                      // 0..63
  const int col0 = (xcd * 2 + (j >= 32 ? 1 : 0)) * 64;
  const int row0 = (j & 31) * 128;

  const int tid = threadIdx.x;
  const int w = tid >> 6;                     // 0..3
  const int lane = tid & 63;
  const int l15 = lane & 15;
  const int l4 = lane >> 4;
  const int wr = (w >> 1) * 64;
  const int wc = (w & 1) * 32;
  const int sr = lane >> 2;
  const int sc = lane & 3;

  floatx4 acc[4][2];
#pragma unroll
  for (int m = 0; m < 4; ++m)
#pragma unroll
    for (int n = 0; n < 2; ++n) acc[m][n] = (floatx4){0.f, 0.f, 0.f, 0.f};

  auto stage = [&](int t) {
    const int buf = t % 3;
    const int k0 = t * 32;
#pragma unroll
    for (int l = 0; l < 2; ++l) {
      const int r = w * 16 + sr + l * 64;
      gload_lds16(A + (size_t)(row0 + r) * K + k0 + ((sc ^ ((r >> 1) & 3)) * 8),
                  (char*)SA[buf] + (w * 16 + l * 64) * 64);
    }
    {
      const int r = w * 16 + sr;
      gload_lds16(Bt + (size_t)(col0 + r) * K + k0 + ((sc ^ ((r >> 1) & 3)) * 8),
                  (char*)SB[buf] + (w * 16) * 64);
    }
  };

  stage(0);
  stage(1);
  asm volatile("s_waitcnt vmcnt(3)" ::: "memory");
  __builtin_amdgcn_s_barrier();

  const int NT = K / 32;  // 32
  for (int t = 0; t < NT; ++t) {
    const unsigned short* sa = SA[t % 3];
    const unsigned short* sb = SB[t % 3];

    short8 af[4], bf[2];
#pragma unroll
    for (int n = 0; n < 2; ++n) {
      const int rb = wc + n * 16 + l15;
      bf[n] = *(const short8*)(sb + rb * 32 + ((l4 ^ ((rb >> 1) & 3)) * 8));
    }
#pragma unroll
    for (int m = 0; m < 4; ++m) {
      const int ra = wr + m * 16 + l15;
      af[m] = *(const short8*)(sa + ra * 32 + ((l4 ^ ((ra >> 1) & 3)) * 8));
    }
    if (t + 2 < NT) stage(t + 2);

    __builtin_amdgcn_s_setprio(1);
#pragma unroll
    for (int m = 0; m < 4; ++m)
#pragma unroll
      for (int n = 0; n < 2; ++n)
        acc[m][n] = __builtin_amdgcn_mfma_f32_16x16x32_bf16(af[m], bf[n], acc[m][n], 0, 0, 0);
    __builtin_amdgcn_s_setprio(0);

    if (t + 1 < NT) {
      if (t + 2 < NT)
        asm volatile("s_waitcnt vmcnt(3)" ::: "memory");
      else
        asm volatile("s_waitcnt vmcnt(0)" ::: "memory");
      __builtin_amdgcn_s_barrier();
    }
  }

  const int rg = l4 * 4;
#pragma unroll
  for (int m = 0; m < 4; ++m) {
#pragma unroll
    for (int n = 0; n < 2; ++n) {
      const int col = col0 + wc + n * 16 + l15;
      const float bv = bias[col];
#pragma unroll
      for (int r = 0; r < 4; ++r) {
        const int row = row0 + wr + m * 16 + rg + r;
        C[(size_t)row * N + col] = acc[m][n][r] + bv;
      }
    }
  }
}

// ---------------------------------------------------------------------------
// MFMA flash attention v9 (best measured: 46.4us): KVBLK=128, 4 waves x 16
// q-rows, paired-qt uniform blocks (17 tiles), dbuf K+V^T (72KB -> 2
// blocks/CU), XCD-local bh, de-shuffled log2 softmax with defer-max, P via
// two k-sub-phases. K swizzle chunk^(row&7); V swizzle chunk^(d&15).
// ---------------------------------------------------------------------------
__global__ __launch_bounds__(256) void flash_mfma_kernel(
    const unsigned short* __restrict__ qkv,
    const unsigned short* __restrict__ vT,
    unsigned short* __restrict__ y) {
  __shared__ unsigned short Ks[2][128 * 64];  // 32KB [token][d-chunk swz]
  __shared__ unsigned short Vs[2][64 * 128];  // 32KB [d][tok-chunk swz]
  __shared__ unsigned short Ps[4][16 * 64];   // 8KB per-wave P (sub-phase)

  const int id = blockIdx.x;
  const int xcd = id & 7;
  const int grp = (id >> 3) & 3;
  const int p = id >> 5;               // 0..15
  const int bh = xcd * 4 + grp;
  const int qtA = 31 - p, qtB = p;
  const int ntA = qtA / 2 + 1, ntB = qtB / 2 + 1;  // total 17 for every block

  const int h = bh & (NHEAD - 1);
  const int b = bh >> 4;
  const int tid = threadIdx.x;
  const int wq = tid >> 6;
  const int lane = tid & 63;
  const int l15 = lane & 15;
  const int l4 = lane >> 4;

  const size_t baseQ = (size_t)(b * TT) * (3 * CC) + h * DHEAD;
  const size_t baseK = baseQ + CC;
  const size_t vbase = (size_t)((b * NHEAD + h) * DHEAD) * TT;

  short8 aqA[2], aqB[2];
  {
    const unsigned short* qp =
        qkv + baseQ + (size_t)(qtA * 64 + wq * 16 + l15) * (3 * CC) + l4 * 8;
    aqA[0] = *(const short8*)(qp);
    aqA[1] = *(const short8*)(qp + 32);
    const unsigned short* qp2 =
        qkv + baseQ + (size_t)(qtB * 64 + wq * 16 + l15) * (3 * CC) + l4 * 8;
    aqB[0] = *(const short8*)(qp2);
    aqB[1] = *(const short8*)(qp2 + 32);
  }

  floatx4 accT[4];
  float m_i = -1e30f, l_i = 0.f;   // l_i per-lane partial
#pragma unroll
  for (int n = 0; n < 4; ++n) accT[n] = (floatx4){0.f, 0.f, 0.f, 0.f};

  // stage tile (128 tokens): per wave 4 K-units (8 rows) + 4 V-units (4 d-rows)
  auto stage = [&](int KT, int BUF) {
#pragma unroll
    for (int uu = 0; uu < 4; ++uu) {
      const int u = uu * 4 + wq;            // 0..15, wave-uniform
      const int kr = u * 8 + (lane >> 3);   // K token row
      gload_lds16(qkv + baseK + (size_t)(KT * 128 + kr) * (3 * CC) +
                      (((lane & 7) ^ (kr & 7)) * 8),
                  (char*)Ks[BUF] + u * 1024);
      const int vd = u * 4 + (lane >> 4);   // V d row
      gload_lds16(vT + vbase + (size_t)vd * TT + KT * 128 +
                      (((lane & 15) ^ (vd & 15)) * 8),
                  (char*)Vs[BUF] + u * 1024);
    }
  };

  auto epilogue = [&](int qt) {
    char* Pw = (char*)Ps[wq];
    float lsum = l_i;
    lsum += __shfl_xor(lsum, 16, 64);
    lsum += __shfl_xor(lsum, 32, 64);
    const float inv = 1.0f / lsum;
#pragma unroll
    for (int nd = 0; nd < 4; ++nd) {
      uintx2 dw;
      dw[0] = cvt_pk_bf16(accT[nd][0] * inv, accT[nd][1] * inv);
      dw[1] = cvt_pk_bf16(accT[nd][2] * inv, accT[nd][3] * inv);
      const int c = nd * 2 + (l4 >> 1);
      *(uintx2*)(Pw + l15 * 128 + ((c ^ (l15 & 7)) * 16) + (l4 & 1) * 8) = dw;
    }
    asm volatile("s_waitcnt lgkmcnt(0)" ::: "memory");
#pragma unroll
    for (int ch = 0; ch < 2; ++ch) {
      const int q16 = lane >> 2;
      const int c = ch * 4 + (lane & 3);
      ushort8 o = *(const ushort8*)(Pw + q16 * 128 + ((c ^ (q16 & 7)) * 16));
      const int qg = qt * 64 + wq * 16 + q16;
      *(ushort8*)(y + (size_t)(b * TT + qg) * CC + h * DHEAD + c * 8) = o;
    }
  };

  const int nt_total = ntA + ntB;  // 17

  stage(0, 0);
  asm volatile("s_waitcnt vmcnt(0)" ::: "memory");
  __builtin_amdgcn_s_barrier();

  for (int t = 0; t < nt_total; ++t) {
    const bool phB = (t >= ntA);
    const int kt = phB ? t - ntA : t;
    const int qminw = (phB ? qtB : qtA) * 64 + wq * 16;
    const int cur = t & 1;
    if (t + 1 < nt_total)
      stage((t + 1 >= ntA) ? t + 1 - ntA : t + 1, cur ^ 1);  // 8 gloads, overlapped

    // ---- S^T = K Q^T : 16 MFMA, sa[f] rows k=f*16+l4*4+r, col q=l15 ----
    floatx4 sa[8];
#pragma unroll
    for (int f = 0; f < 8; ++f) sa[f] = (floatx4){0.f, 0.f, 0.f, 0.f};

    __builtin_amdgcn_s_setprio(1);
#pragma unroll
    for (int kc = 0; kc < 2; ++kc) {
      const short8 aq = phB ? aqB[kc] : aqA[kc];
#pragma unroll
      for (int f = 0; f < 8; ++f) {
        const int row = 16 * f + l15;
        short8 bk = *(const short8*)(Ks[cur] + row * 64 +
                                     ((kc * 4 + l4) ^ (row & 7)) * 8);
        sa[f] = __builtin_amdgcn_mfma_f32_16x16x32_bf16(bk, aq, sa[f], 0, 0, 0);
      }
    }
    __builtin_amdgcn_s_setprio(0);

    // ---- mask + de-shuffled online softmax (log2 domain) ----
    const int qg = qminw + l15;
    if (kt * 128 + 127 > qminw) {
#pragma unroll
      for (int f = 0; f < 8; ++f)
#pragma unroll
        for (int r = 0; r < 4; ++r) {
          const int kg = kt * 128 + f * 16 + l4 * 4 + r;
          if (kg > qg) sa[f][r] = -1e30f;
        }
    }
    float rm = -1e30f;
#pragma unroll
    for (int f = 0; f < 8; ++f)
      rm = fmaxf(rm, fmaxf(fmaxf(sa[f][0], sa[f][1]), fmaxf(sa[f][2], sa[f][3])));

    float rs = 0.f;
    if (__all(rm <= m_i + 8.0f)) {
#pragma unroll
      for (int f = 0; f < 8; ++f)
#pragma unroll
        for (int r = 0; r < 4; ++r) {
          const float pv = __builtin_amdgcn_exp2f(sa[f][r] - m_i);
          sa[f][r] = pv;
          rs += pv;
        }
      l_i += rs;
    } else {
      rm = fmaxf(rm, __shfl_xor(rm, 16, 64));
      rm = fmaxf(rm, __shfl_xor(rm, 32, 64));
      const float mn = fmaxf(m_i, rm);
      const float scale = __builtin_amdgcn_exp2f(m_i - mn);
#pragma unroll
      for (int f = 0; f < 8; ++f)
#pragma unroll
        for (int r = 0; r < 4; ++r) {
          const float pv = __builtin_amdgcn_exp2f(sa[f][r] - mn);
          sa[f][r] = pv;
          rs += pv;
        }
      l_i = l_i * scale + rs;
      m_i = mn;
#pragma unroll
      for (int nd = 0; nd < 4; ++nd) accT[nd] *= scale;
    }

    // ---- P -> LDS -> PV in two k-sub-phases (64 tokens each) ----
    char* Pg = (char*)Ps[wq];
#pragma unroll
    for (int ph = 0; ph < 2; ++ph) {
#pragma unroll
      for (int fp = 0; fp < 4; ++fp) {
        const int f = ph * 4 + fp;
        uintx2 dw;
        dw[0] = cvt_pk_bf16(sa[f][0], sa[f][1]);
        dw[1] = cvt_pk_bf16(sa[f][2], sa[f][3]);
        const int c = fp * 2 + (l4 >> 1);
        *(uintx2*)(Pg + l15 * 128 + ((c ^ (l15 & 7)) * 16) + (l4 & 1) * 8) = dw;
      }
      asm volatile("s_waitcnt lgkmcnt(0)" ::: "memory");  // same-wave RAW

      short8 pb[2];
#pragma unroll
      for (int kc2 = 0; kc2 < 2; ++kc2) {
        const int c = kc2 * 4 + l4;
        pb[kc2] = *(const short8*)(Pg + l15 * 128 + ((c ^ (l15 & 7)) * 16));
      }

      __builtin_amdgcn_s_setprio(1);
#pragma unroll
      for (int kc2 = 0; kc2 < 2; ++kc2) {
        const int kcg = ph * 2 + kc2;   // global 32-token chunk 0..3
#pragma unroll
        for (int nd = 0; nd < 4; ++nd) {
          const int row = 16 * nd + l15;
          short8 vb = *(const short8*)(Vs[cur] + row * 128 +
                                       (((kcg * 4 + l4) ^ (row & 15)) * 8));
          accT[nd] = __builtin_amdgcn_mfma_f32_16x16x32_bf16(vb, pb[kc2], accT[nd], 0, 0, 0);
        }
      }
      __builtin_amdgcn_s_setprio(0);
    }

    asm volatile("s_waitcnt vmcnt(0)" ::: "memory");
    __builtin_amdgcn_s_barrier();

    if (t == ntA - 1) {
      epilogue(qtA);
      m_i = -1e30f;
      l_i = 0.f;
#pragma unroll
      for (int n = 0; n < 4; ++n) accT[n] = (floatx4){0.f, 0.f, 0.f, 0.f};
    }
  }

  epilogue(qtB);
}

extern "C" void kernel_launch(void* const* d_in, const int* in_sizes, int n_in,
                              void* d_out, int out_size, void* d_ws, size_t ws_size,
                              hipStream_t stream) {
  const float* x      = (const float*)d_in[0];
  const float* W_attn = (const float*)d_in[1];
  const float* b_attn = (const float*)d_in[2];
  const float* W_proj = (const float*)d_in[3];
  const float* b_proj = (const float*)d_in[4];
  float* out = (float*)d_out;

  const int M = BB * TT;  // 4096
  const float SCL = 0.125f * 1.44269504089f;  // 1/sqrt(64) * log2(e)

  // workspace layout (ushort units)
  unsigned short* qkvb = (unsigned short*)d_ws;          // M * 3C
  unsigned short* xb   = qkvb + (size_t)M * 3 * CC;      // M * C
  unsigned short* Wat  = xb + (size_t)M * CC;            // 3C * C
  unsigned short* Wpt  = Wat + (size_t)3 * CC * CC;      // C * C
  unsigned short* yb   = Wpt + (size_t)CC * CC;          // M * C
  unsigned short* vTb  = yb + (size_t)M * CC;            // B*H*D*T
  float* bscl = (float*)(vTb + (size_t)BB * NHEAD * DHEAD * TT);  // 3C floats

  prep_kernel<<<8204, 256, 0, stream>>>(x, W_attn, b_attn, W_proj,
                                        xb, Wat, Wpt, bscl, SCL);

  // GEMM1: qkv = x @ W_attn + b_attn (128x192, 512 blocks = 2/CU, counted)
  gemm1_kernel<<<512, 256, 0, stream>>>(xb, Wat, bscl, qkvb, M, 3 * CC, CC);

  // V -> vT[b][h][d][T]
  {
    dim3 grid(TT / 64, BB * NHEAD);
    transpose_v_kernel<<<grid, 256, 0, stream>>>(qkvb, vTb);
  }

  // MFMA flash attention (paired-qt, KVBLK=128, dbuf, XCD-local)
  flash_mfma_kernel<<<512, 256, 0, stream>>>(qkvb, vTb, yb);

  // GEMM2: out = y @ W_proj + b_proj (counted-vmcnt pipeline, fp32 out)
  gemm2_kernel<<<512, 256, 0, stream>>>(yb, Wpt, b_proj, out, M, CC, CC);
}